// Round 5
// baseline (4484.339 us; speedup 1.0000x reference)
//
#include <hip/hip_runtime.h>

#define BATCH 64
#define SEQT  512
#define DIM   1024

#define JB   32                 // j-rows per block
#define BB   8                  // batches per block
#define NJG  (DIM / JB)         // 32 j-groups (column size)
#define NBG  (BATCH / BB)       // 8 independent columns
#define NBLK (NJG * NBG)        // 256 blocks
#define NTHR 512
#define UPITCH 34               // 8B-aligned rows, (2k+c)%32 banks -> ~2-way (free)

// dynamic LDS carve-up (floats)
#define LDS_U    (DIM * UPITCH)          // 139264 B
#define LDS_RED  (8 * 256)               // 8192 B
#define LDS_H    (8 * 256)               // 8192 B: 8 waves x 256 floats (1KB chunk each)
#define LDS_BYTES ((LDS_U + LDS_RED + LDS_H) * 4)   // 155648 < 163840

typedef unsigned long long ull;
typedef float f4 __attribute__((ext_vector_type(4)));

union F2U {
    ull u;
    float f[2];
};

// ---------------------------------------------------------------------------
// Phase 1: wx = x @ W_w^T + W_b  (fp32, 64x64 tile, BK=16, 4x4 micro-tile)
// ---------------------------------------------------------------------------
__global__ __launch_bounds__(256) void gemm_wx(const float* __restrict__ x,
                                               const float* __restrict__ Ww,
                                               const float* __restrict__ Wb,
                                               float* __restrict__ out) {
    __shared__ float As[16][64];
    __shared__ float Bs[16][64];

    const int tid = threadIdx.x;
    const int nb = blockIdx.x & 15;
    const int mb = blockIdx.x >> 4;
    const int m0 = mb * 64, n0 = nb * 64;
    const int tx = tid & 15, ty = tid >> 4;
    const int r0 = ty * 4, c0 = tx * 4;

    float acc[4][4] = {};

    const int lrow = tid >> 2;
    const int lk = (tid & 3) * 4;
    const float* xa = x + (size_t)(m0 + lrow) * DIM + lk;
    const float* wa = Ww + (size_t)(n0 + lrow) * DIM + lk;

    for (int kt = 0; kt < DIM / 16; ++kt) {
        float4 av = *(const float4*)xa;
        float4 bv = *(const float4*)wa;
        __syncthreads();
        As[lk + 0][lrow] = av.x; As[lk + 1][lrow] = av.y;
        As[lk + 2][lrow] = av.z; As[lk + 3][lrow] = av.w;
        Bs[lk + 0][lrow] = bv.x; Bs[lk + 1][lrow] = bv.y;
        Bs[lk + 2][lrow] = bv.z; Bs[lk + 3][lrow] = bv.w;
        __syncthreads();
#pragma unroll
        for (int kk = 0; kk < 16; ++kk) {
            float4 a = *(const float4*)&As[kk][r0];
            float4 b = *(const float4*)&Bs[kk][c0];
            acc[0][0] += a.x * b.x; acc[0][1] += a.x * b.y; acc[0][2] += a.x * b.z; acc[0][3] += a.x * b.w;
            acc[1][0] += a.y * b.x; acc[1][1] += a.y * b.y; acc[1][2] += a.y * b.z; acc[1][3] += a.y * b.w;
            acc[2][0] += a.z * b.x; acc[2][1] += a.z * b.y; acc[2][2] += a.z * b.z; acc[2][3] += a.z * b.w;
            acc[3][0] += a.w * b.x; acc[3][1] += a.w * b.y; acc[3][2] += a.w * b.z; acc[3][3] += a.w * b.w;
        }
        xa += 16; wa += 16;
    }

    float4 wb = *(const float4*)(Wb + n0 + c0);
#pragma unroll
    for (int i = 0; i < 4; ++i) {
        float4 o;
        o.x = acc[i][0] + wb.x; o.y = acc[i][1] + wb.y;
        o.z = acc[i][2] + wb.z; o.w = acc[i][3] + wb.w;
        *(float4*)(out + (size_t)(m0 + r0 + i) * DIM + n0 + c0) = o;
    }
}

// ---------------------------------------------------------------------------
// Phase 2: persistent cooperative scan, U-slice resident in LDS.
// Round 9: tag-in-data protocol (flags eliminated).
//  - publisher adds a step-keyed offset to each h value: off(t) in {2,6}
//    alternating per reuse of the same double buffer; tanh in (-1,1) makes
//    [1,3] / [5,7] / raw-0 disjoint with threshold 1.5.  Consumers poll the
//    DATA (4 x dwordx4 sc0 sc1) until all 16 floats are in-range.  Removes
//    the flag array, the flag-visibility RT, and the publisher ack RT: no
//    returning exchanges needed, each 8B atomic store self-validates, and
//    there is no cross-location ordering left to race.
//  - publish moved BEFORE barrier B: reducers pair (b even, b odd) values
//    via shfl_down(32) and store directly; val[] gone.  Barrier B now only
//    protects red[] WAR and is off the inter-block critical path.
//  - WAR safety (same induction as rounds 5-8): block X writes buffer P at
//    step t only after its barrier A(t), which requires all 32 producers
//    published t-1, each after its own barrier A(t-1), which postdates every
//    wave's t-1 loads of P.
//  - precision: offset add/sub costs <= ulp(6)/2 ~ 2.4e-7 per step; the
//    recurrence is contractive (tanh); accumulated ~1e-5 << 3.9e-3 tol.
// ---------------------------------------------------------------------------
__global__ __launch_bounds__(NTHR, 1) void rnn_scan3(
    const float* __restrict__ Uw,   // [j][k] original layout
    const float* __restrict__ Ub,
    const float* __restrict__ bias,
    float* __restrict__ out,        // [B][T][D] holds wx, overwritten; +hT tail
    float* __restrict__ h0,         // [bg][k][8] column-contiguous
    float* __restrict__ h1,         // [bg][k][8]
    unsigned* __restrict__ bar) {   // unused (kept for launch ABI); ws zeroed
    extern __shared__ float lds[];
    float* Ulds = lds;                    // [DIM][UPITCH], Ulds[k][c]=Uw[j0+c][k]
    float* red  = lds + LDS_U;            // [8 waves][256]
    float* hbuf = red + LDS_RED;          // [8 waves][256] staging chunk

    const int tid = threadIdx.x;
    const int bg = blockIdx.x & 7;
    const int jg = blockIdx.x >> 3;
    const int j0 = jg * JB;
    const int b0 = bg * BB;

    // one-time LDS fill of this block's U-slice (transposed to [k][j])
    {
        int c = tid & 31;
        int kc = (tid >> 5) << 6;  // 16 chunks of 64 k
        const float* src = Uw + (size_t)(j0 + c) * DIM + kc;
#pragma unroll
        for (int i = 0; i < 16; ++i) {
            float4 v = *(const float4*)(src + i * 4);
            int k = kc + i * 4;
            Ulds[(k + 0) * UPITCH + c] = v.x;
            Ulds[(k + 1) * UPITCH + c] = v.y;
            Ulds[(k + 2) * UPITCH + c] = v.z;
            Ulds[(k + 3) * UPITCH + c] = v.w;
        }
    }

    float cst = 0.f;
    if (tid < 256) {
        int jl = tid & 31;
        cst = Ub[j0 + jl] + bias[j0 + jl];
    }
    __syncthreads();

    const int ksl = tid & 3;
    const int jt  = (tid >> 2) & 7;
    const int bt  = (tid >> 5) & 1;
    const int w   = tid >> 6;
    const int ln  = tid & 63;

    // wave w's k-range: [128w, 128w+128).  Lane computes k = 128w + ksl + 4i.
    const float* uw_p0 = Ulds + (size_t)(128 * w + ksl) * UPITCH + jt * 4;
    const size_t colf = (size_t)bg * 8192;               // column float offset
    const size_t lf0 = (size_t)w * 1024 + (size_t)ln * 4;
    float* hstg = hbuf + w * 256 + ln * 4;               // staging write slot
    const float* hrd = hbuf + w * 256 + ksl * 8 + bt * 4;  // staging read base

    for (int t = 0; t < SEQT; ++t) {
        const float* hc_col = ((t & 1) ? h1 : h0) + colf;
        float* hn_col = ((t & 1) ? h0 : h1) + colf;
        // offset of data CONSUMED at t (0: raw memset zeros); publisher uses off(t+1)
        const float offc = (t == 0) ? 0.f : ((t & 2) ? 6.f : 2.f);

        // prefetch this step's wx early (overlaps the poll + k-loop)
        float wxv = 0.f;
        size_t oidx = 0;
        if (tid < 256) {
            int jl = tid & 31, bl = tid >> 5;
            oidx = ((size_t)(b0 + bl) * SEQT + t) * DIM + (j0 + jl);
            wxv = out[oidx];
        }

        // poll-on-data: loads ARE the poll; exit when all 16 floats in-range
        const float* hp = hc_col + lf0;
        f4 hv0, hv1, hv2, hv3;
        for (;;) {
            asm volatile("global_load_dwordx4 %0, %1, off sc0 sc1" : "=v"(hv0) : "v"(hp));
            asm volatile("global_load_dwordx4 %0, %1, off sc0 sc1" : "=v"(hv1) : "v"(hp + 256));
            asm volatile("global_load_dwordx4 %0, %1, off sc0 sc1" : "=v"(hv2) : "v"(hp + 512));
            asm volatile("global_load_dwordx4 %0, %1, off sc0 sc1" : "=v"(hv3) : "v"(hp + 768));
            asm volatile("s_waitcnt vmcnt(0)"
                         : "+v"(hv0), "+v"(hv1), "+v"(hv2), "+v"(hv3)
                         :: "memory");
            if (t == 0) break;
#define CK(X) (__builtin_fabsf((X) - offc) >= 1.5f)
            bool bad = CK(hv0.x) || CK(hv0.y) || CK(hv0.z) || CK(hv0.w) ||
                       CK(hv1.x) || CK(hv1.y) || CK(hv1.z) || CK(hv1.w) ||
                       CK(hv2.x) || CK(hv2.y) || CK(hv2.z) || CK(hv2.w) ||
                       CK(hv3.x) || CK(hv3.y) || CK(hv3.z) || CK(hv3.w);
#undef CK
            if (__ballot(bad) == 0) break;
        }
        __builtin_amdgcn_sched_barrier(0);
        {   // strip the tag offset
            f4 o4 = {offc, offc, offc, offc};
            hv0 -= o4; hv1 -= o4; hv2 -= o4; hv3 -= o4;
        }

        float acc[4][4] = {};   // [jj][bb]
        const float* up = uw_p0;

#pragma unroll
        for (int li = 0; li < 4; ++li) {      // chunk li covers i = 8*li .. 8*li+7
            f4 hv = (li == 0) ? hv0 : (li == 1) ? hv1 : (li == 2) ? hv2 : hv3;
            asm volatile("" ::: "memory");    // order: prior chunk's reads before this write
            *(f4*)hstg = hv;                  // wave-private staging
            asm volatile("" ::: "memory");    // order: write before this chunk's reads
#pragma unroll
            for (int j = 0; j < 8; ++j) {     // i = 8*li + j, k = 128w + 32li + ksl + 4j
                float2 ua = *(const float2*)up;
                float2 ub = *(const float2*)(up + 2);
                f4 h4 = *(const f4*)(hrd + j * 32);
                acc[0][0] += ua.x * h4.x; acc[0][1] += ua.x * h4.y; acc[0][2] += ua.x * h4.z; acc[0][3] += ua.x * h4.w;
                acc[1][0] += ua.y * h4.x; acc[1][1] += ua.y * h4.y; acc[1][2] += ua.y * h4.z; acc[1][3] += ua.y * h4.w;
                acc[2][0] += ub.x * h4.x; acc[2][1] += ub.x * h4.y; acc[2][2] += ub.x * h4.z; acc[2][3] += ub.x * h4.w;
                acc[3][0] += ub.y * h4.x; acc[3][1] += ub.y * h4.y; acc[3][2] += ub.y * h4.z; acc[3][3] += ub.y * h4.w;
                up += 4 * UPITCH;
            }
        }

        // reduce the 4 in-wave k-slots (lane bits 0,1)
#pragma unroll
        for (int jj = 0; jj < 4; ++jj)
#pragma unroll
            for (int bb = 0; bb < 4; ++bb) {
                float v = acc[jj][bb];
                v += __shfl_xor(v, 1, 64);
                v += __shfl_xor(v, 2, 64);
                acc[jj][bb] = v;
            }
        if (ksl == 0) {
#pragma unroll
            for (int jj = 0; jj < 4; ++jj)
#pragma unroll
                for (int bb = 0; bb < 4; ++bb)
                    red[w * 256 + (bt * 4 + bb) * 32 + jt * 4 + jj] = acc[jj][bb];
        }
        __syncthreads();   // A

        if (tid < 256) {  // cross-wave reduce + tanh + out write + publish
            float s = 0.f;
#pragma unroll
            for (int ww = 0; ww < 8; ++ww) s += red[ww * 256 + tid];
            float v = tanhf(wxv + s + cst);
            out[oidx] = v;
            if (t == SEQT - 1)
                out[(size_t)BATCH * SEQT * DIM + (size_t)(b0 + (tid >> 5)) * DIM + (j0 + (tid & 31))] = v;
            // pair (b even, b odd) within the wave: lane L gets lane L+32's v
            float vpart = __shfl_down(v, 32, 64);
            if (t < SEQT - 1 && (tid & 32) == 0) {
                const float offp = (((t + 1) & 2) ? 6.f : 2.f);
                F2U p;
                p.f[0] = v + offp;
                p.f[1] = vpart + offp;
                int jl = tid & 31, q = tid >> 6;   // this wave owns b = 2q, 2q+1
                __hip_atomic_store((ull*)hn_col + (size_t)(j0 + jl) * 4 + q, p.u,
                                   __ATOMIC_RELAXED, __HIP_MEMORY_SCOPE_AGENT);
            }
        }
        __syncthreads();   // B — only protects red[] WAR; off the publish path
    }
}

// ---------------------------------------------------------------------------
extern "C" void kernel_launch(void* const* d_in, const int* in_sizes, int n_in,
                              void* d_out, int out_size, void* d_ws, size_t ws_size,
                              hipStream_t stream) {
    const float* x    = (const float*)d_in[0];
    const float* W_w  = (const float*)d_in[1];
    const float* W_b  = (const float*)d_in[2];
    const float* U_w  = (const float*)d_in[3];
    const float* U_b  = (const float*)d_in[4];
    const float* bias = (const float*)d_in[5];
    float* out = (float*)d_out;

    // ws: [0,64K) spare ; [64K, +256K) h0 ; then h1
    unsigned* bar = (unsigned*)d_ws;
    float* h0 = (float*)((char*)d_ws + 65536);
    float* h1 = h0 + (size_t)DIM * BATCH;

    hipMemsetAsync(d_ws, 0, 65536 + 2 * (size_t)DIM * BATCH * sizeof(float), stream);

    gemm_wx<<<dim3((32768 / 64) * (DIM / 64)), dim3(256), 0, stream>>>(x, W_w, W_b, out);

    static bool attr_done = false;
    if (!attr_done) {
        hipFuncSetAttribute((const void*)rnn_scan3,
                            hipFuncAttributeMaxDynamicSharedMemorySize, LDS_BYTES);
        attr_done = true;
    }

    void* args[] = {(void*)&U_w, (void*)&U_b, (void*)&bias,
                    (void*)&out, (void*)&h0, (void*)&h1, (void*)&bar};
    hipLaunchCooperativeKernel((void*)rnn_scan3, dim3(NBLK), dim3(NTHR), args,
                               LDS_BYTES, stream);
}

// Round 6
// 3127.058 us; speedup vs baseline: 1.4340x; 1.4340x over previous
//
#include <hip/hip_runtime.h>

#define BATCH 64
#define SEQT  512
#define DIM   1024

#define JB   32                 // j-rows per block
#define BB   8                  // batches per block
#define NJG  (DIM / JB)         // 32 j-groups (column size)
#define NBG  (BATCH / BB)       // 8 independent columns
#define NBLK (NJG * NBG)        // 256 blocks
#define NTHR 512
#define UPITCH 34               // 8B-aligned rows, (2k+c)%32 banks -> ~2-way (free)

// dynamic LDS: init phase uses Ulds [DIM][UPITCH] = 139264 B; after the U
// registers are filled, the SAME memory is re-carved as red/val/hbuf (17.4 KB).
#define LDS_BYTES (DIM * UPITCH * 4)     // 139264

typedef unsigned long long ull;
typedef float f4 __attribute__((ext_vector_type(4)));

union F2U {
    ull u;
    float f[2];
};

// ---------------------------------------------------------------------------
// Phase 1: wx = x @ W_w^T + W_b  (fp32, 128x128 tile, BK=16, 8x8 micro-tile)
// Round 10: upgraded from 64x64/4x4 (was ~2x off the 437us fp32 roofline).
// ---------------------------------------------------------------------------
__global__ __launch_bounds__(256) void gemm_wx(const float* __restrict__ x,
                                               const float* __restrict__ Ww,
                                               const float* __restrict__ Wb,
                                               float* __restrict__ out) {
    __shared__ float As[16][128];
    __shared__ float Bs[16][128];

    const int tid = threadIdx.x;
    const int nb = blockIdx.x & 7;       // 1024/128
    const int mb = blockIdx.x >> 3;      // 32768/128
    const int m0 = mb * 128, n0 = nb * 128;
    const int tx = tid & 15, ty = tid >> 4;

    float acc[8][8] = {};   // rows ty*4+{0..3}(+64), cols tx*4+{0..3}(+64)

    const int lrow = tid >> 1;           // 0..127
    const int lk = (tid & 1) * 8;        // 0 or 8
    const float* xa = x + (size_t)(m0 + lrow) * DIM + lk;
    const float* wa = Ww + (size_t)(n0 + lrow) * DIM + lk;

    for (int kt = 0; kt < DIM / 16; ++kt) {
        float4 a0 = *(const float4*)xa, a1 = *(const float4*)(xa + 4);
        float4 b0 = *(const float4*)wa, b1 = *(const float4*)(wa + 4);
        __syncthreads();
        As[lk + 0][lrow] = a0.x; As[lk + 1][lrow] = a0.y;
        As[lk + 2][lrow] = a0.z; As[lk + 3][lrow] = a0.w;
        As[lk + 4][lrow] = a1.x; As[lk + 5][lrow] = a1.y;
        As[lk + 6][lrow] = a1.z; As[lk + 7][lrow] = a1.w;
        Bs[lk + 0][lrow] = b0.x; Bs[lk + 1][lrow] = b0.y;
        Bs[lk + 2][lrow] = b0.z; Bs[lk + 3][lrow] = b0.w;
        Bs[lk + 4][lrow] = b1.x; Bs[lk + 5][lrow] = b1.y;
        Bs[lk + 6][lrow] = b1.z; Bs[lk + 7][lrow] = b1.w;
        __syncthreads();
#pragma unroll
        for (int kk = 0; kk < 16; ++kk) {
            float4 ax0 = *(const float4*)&As[kk][ty * 4];
            float4 ax1 = *(const float4*)&As[kk][ty * 4 + 64];
            float4 bx0 = *(const float4*)&Bs[kk][tx * 4];
            float4 bx1 = *(const float4*)&Bs[kk][tx * 4 + 64];
            float ar[8] = {ax0.x, ax0.y, ax0.z, ax0.w, ax1.x, ax1.y, ax1.z, ax1.w};
            float br[8] = {bx0.x, bx0.y, bx0.z, bx0.w, bx1.x, bx1.y, bx1.z, bx1.w};
#pragma unroll
            for (int r = 0; r < 8; ++r)
#pragma unroll
                for (int c = 0; c < 8; ++c)
                    acc[r][c] += ar[r] * br[c];
        }
        xa += 16; wa += 16;
    }

    float4 wb0 = *(const float4*)(Wb + n0 + tx * 4);
    float4 wb1 = *(const float4*)(Wb + n0 + tx * 4 + 64);
#pragma unroll
    for (int r = 0; r < 8; ++r) {
        int row = m0 + ty * 4 + (r & 3) + ((r >> 2) << 6);
        float* op = out + (size_t)row * DIM + n0;
        float4 o0, o1;
        o0.x = acc[r][0] + wb0.x; o0.y = acc[r][1] + wb0.y;
        o0.z = acc[r][2] + wb0.z; o0.w = acc[r][3] + wb0.w;
        o1.x = acc[r][4] + wb1.x; o1.y = acc[r][5] + wb1.y;
        o1.z = acc[r][6] + wb1.z; o1.w = acc[r][7] + wb1.w;
        *(float4*)(op + tx * 4) = o0;
        *(float4*)(op + tx * 4 + 64) = o1;
    }
}

// ---------------------------------------------------------------------------
// Phase 2: persistent cooperative scan.
// Round 10 (round-9's data-poll regressed from cache-line ping-pong; round-8
// flag protocol restored verbatim).  Changes vs round 8:
//  - U promoted to REGISTERS ur[32][4] (each lane re-read the same 128 U
//    floats from LDS every step = the whole 136KB slice per block per step).
//    One-time: fill Ulds (coalesced), reg-read, then the Ulds memory is
//    re-carved as red/val/hbuf (aliased; separated by barriers).
//  - out[] wx-overwrite moved AFTER the flag store: publishers' waitcnt ack
//    no longer waits for an HBM write ack on the critical path.
//  - everything else (poll, publish, staging, reduction) is round-8 verbatim.
// ---------------------------------------------------------------------------
__global__ __launch_bounds__(NTHR, 1) void rnn_scan3(
    const float* __restrict__ Uw,   // [j][k] original layout
    const float* __restrict__ Ub,
    const float* __restrict__ bias,
    float* __restrict__ out,        // [B][T][D] holds wx, overwritten; +hT tail
    float* __restrict__ h0,         // [bg][k][8] column-contiguous
    float* __restrict__ h1,         // [bg][k][8]
    unsigned* __restrict__ bar) {   // flags: [bg][jg*2+pubwave] spaced 64B, zeroed
    extern __shared__ float lds[];
    float* Ulds = lds;                    // init phase ONLY: [DIM][UPITCH]
    float* red  = lds;                    // run phase: [8 waves][256]  (8 KB)
    float* val  = lds + 2048;             // [256]                      (1 KB)
    float* hbuf = lds + 2304;             // [8 waves][256]             (8 KB)

    const int tid = threadIdx.x;
    const int bg = blockIdx.x & 7;
    const int jg = blockIdx.x >> 3;
    const int j0 = jg * JB;
    const int b0 = bg * BB;

    // one-time LDS fill of this block's U-slice (transposed to [k][j])
    {
        int c = tid & 31;
        int kc = (tid >> 5) << 6;  // 16 chunks of 64 k
        const float* src = Uw + (size_t)(j0 + c) * DIM + kc;
#pragma unroll
        for (int i = 0; i < 16; ++i) {
            float4 v = *(const float4*)(src + i * 4);
            int k = kc + i * 4;
            Ulds[(k + 0) * UPITCH + c] = v.x;
            Ulds[(k + 1) * UPITCH + c] = v.y;
            Ulds[(k + 2) * UPITCH + c] = v.z;
            Ulds[(k + 3) * UPITCH + c] = v.w;
        }
    }

    float cst = 0.f;
    if (tid < 256) {
        int jl = tid & 31;
        cst = Ub[j0 + jl] + bias[j0 + jl];
    }
    __syncthreads();

    const int ksl = tid & 3;
    const int jt  = (tid >> 2) & 7;
    const int bt  = (tid >> 5) & 1;
    const int w   = tid >> 6;
    const int ln  = tid & 63;

    // one-time: pull this lane's 128 U values into registers, then the Ulds
    // region is dead and re-used as red/val/hbuf.
    float ur[32][4];
    {
        const float* up = Ulds + (size_t)(128 * w + ksl) * UPITCH + jt * 4;
#pragma unroll
        for (int i = 0; i < 32; ++i) {
            float2 a = *(const float2*)up;
            float2 b = *(const float2*)(up + 2);
            ur[i][0] = a.x; ur[i][1] = a.y; ur[i][2] = b.x; ur[i][3] = b.y;
            up += 4 * UPITCH;
        }
    }
    __syncthreads();   // after this, red/val/hbuf may overwrite Ulds

    const size_t colf = (size_t)bg * 8192;               // column float offset
    const size_t lf0 = (size_t)w * 1024 + (size_t)ln * 4;
    float* hstg = hbuf + w * 256 + ln * 4;               // staging write slot
    const float* hrd = hbuf + w * 256 + ksl * 8 + bt * 4;  // staging read base
    unsigned* flagbase = bar + (size_t)bg * 1024;        // 4KB per column
    unsigned* myfp = flagbase + (size_t)(8 * w + (ln & 7)) * 16;  // wave's 8 deps

    ull junk = 0;

    for (int t = 0; t < SEQT; ++t) {
        const float* hc_col = ((t & 1) ? h1 : h0) + colf;
        float* hn_col = ((t & 1) ? h0 : h1) + colf;

        // prefetch this step's wx early (latency hidden behind poll + k-loop)
        float wxv = 0.f;
        size_t oidx = 0;
        if (tid < 256) {
            int jl = tid & 31, bl = tid >> 5;
            oidx = ((size_t)(b0 + bl) * SEQT + t) * DIM + (j0 + jl);
            wxv = out[oidx];
        }

        // per-wave sync: wait only for the 4 producer blocks this wave reads
        if (t > 0) {
            unsigned want = (unsigned)t;
            unsigned f;
            do {
                f = want;
                if (ln < 8)
                    f = __hip_atomic_load(myfp, __ATOMIC_RELAXED, __HIP_MEMORY_SCOPE_AGENT);
            } while (__ballot(f < want));
        }
        asm volatile("" ::: "memory");       // loads must not hoist above poll
        __builtin_amdgcn_sched_barrier(0);

        // 4 x 16B bypass loads: the wave's whole k-slice, zero redundancy
        const float* hp = hc_col + lf0;
        f4 hv0, hv1, hv2, hv3;
        asm volatile("global_load_dwordx4 %0, %1, off sc0 sc1" : "=v"(hv0) : "v"(hp));
        asm volatile("global_load_dwordx4 %0, %1, off sc0 sc1" : "=v"(hv1) : "v"(hp + 256));
        asm volatile("global_load_dwordx4 %0, %1, off sc0 sc1" : "=v"(hv2) : "v"(hp + 512));
        asm volatile("global_load_dwordx4 %0, %1, off sc0 sc1" : "=v"(hv3) : "v"(hp + 768));
        asm volatile("s_waitcnt vmcnt(0)"
                     : "+v"(hv0), "+v"(hv1), "+v"(hv2), "+v"(hv3)
                     :: "memory");
        __builtin_amdgcn_sched_barrier(0);

        float acc[4][4] = {};   // [jj][bb]

#pragma unroll
        for (int li = 0; li < 4; ++li) {      // chunk li covers i = 8*li .. 8*li+7
            f4 hv = (li == 0) ? hv0 : (li == 1) ? hv1 : (li == 2) ? hv2 : hv3;
            asm volatile("" ::: "memory");    // order: prior chunk's reads before this write
            *(f4*)hstg = hv;                  // wave-private staging
            asm volatile("" ::: "memory");    // order: write before this chunk's reads
#pragma unroll
            for (int j = 0; j < 8; ++j) {     // i = 8*li + j, k = 128w + 32li + ksl + 4j
                const int i = li * 8 + j;
                f4 h4 = *(const f4*)(hrd + j * 32);
                acc[0][0] += ur[i][0] * h4.x; acc[0][1] += ur[i][0] * h4.y; acc[0][2] += ur[i][0] * h4.z; acc[0][3] += ur[i][0] * h4.w;
                acc[1][0] += ur[i][1] * h4.x; acc[1][1] += ur[i][1] * h4.y; acc[1][2] += ur[i][1] * h4.z; acc[1][3] += ur[i][1] * h4.w;
                acc[2][0] += ur[i][2] * h4.x; acc[2][1] += ur[i][2] * h4.y; acc[2][2] += ur[i][2] * h4.z; acc[2][3] += ur[i][2] * h4.w;
                acc[3][0] += ur[i][3] * h4.x; acc[3][1] += ur[i][3] * h4.y; acc[3][2] += ur[i][3] * h4.z; acc[3][3] += ur[i][3] * h4.w;
            }
        }

        // reduce the 4 in-wave k-slots (lane bits 0,1)
#pragma unroll
        for (int jj = 0; jj < 4; ++jj)
#pragma unroll
            for (int bb = 0; bb < 4; ++bb) {
                float v = acc[jj][bb];
                v += __shfl_xor(v, 1, 64);
                v += __shfl_xor(v, 2, 64);
                acc[jj][bb] = v;
            }
        if (ksl == 0) {
#pragma unroll
            for (int jj = 0; jj < 4; ++jj)
#pragma unroll
                for (int bb = 0; bb < 4; ++bb)
                    red[w * 256 + (bt * 4 + bb) * 32 + jt * 4 + jj] = acc[jj][bb];
        }
        __syncthreads();   // A

        float v = 0.f;
        if (tid < 256) {  // cross-wave reduce + tanh (j-fast); out write DEFERRED
            float s = 0.f;
#pragma unroll
            for (int ww = 0; ww < 8; ++ww) s += red[ww * 256 + tid];
            v = tanhf(wxv + s + cst);
            val[tid] = v;
            if (t == SEQT - 1)
                out[(size_t)BATCH * SEQT * DIM + (size_t)(b0 + (tid >> 5)) * DIM + (j0 + (tid & 31))] = v;
        }
        __syncthreads();   // B

        if (tid < 128) {  // publish h_col[k][8] as returning 8B exchanges (waves 0,1)
            int jl = tid >> 2, m = tid & 3;
            F2U p;
            p.f[0] = val[(2 * m + 0) * 32 + jl];
            p.f[1] = val[(2 * m + 1) * 32 + jl];
            ull old = __hip_atomic_exchange(
                (ull*)hn_col + (size_t)(j0 + jl) * 4 + m,
                p.u, __ATOMIC_RELAXED, __HIP_MEMORY_SCOPE_AGENT);
            junk ^= old;  // force returning form; consumed after the loop

            if (t < SEQT - 1) {
                // wave-local: this wave's exchanges acked AT the coherent
                // point (only the exchanges are outstanding now — the wx
                // out-store is issued AFTER the flag), then the wave's flag.
                __builtin_amdgcn_s_waitcnt(0);
                if ((tid & 63) == 0)
                    __hip_atomic_store(flagbase + ((size_t)jg * 2 + (tid >> 6)) * 16,
                                       (unsigned)(t + 1),
                                       __ATOMIC_RELAXED, __HIP_MEMORY_SCOPE_AGENT);
            }
        }
        asm volatile("" ::: "memory");   // keep the out store AFTER the flag
        if (tid < 256) out[oidx] = v;    // wx overwrite, off the ack path
        // no barrier C: waves proceed straight into step t+1's per-wave poll
    }

    // impossible (NaN-pair pattern tanh can never produce) — keeps the
    // exchange returns live so vmcnt acks are real coherent-point acks.
    if (junk == 0xFFF00001FFF00002ULL) out[0] = -1.0f;
}

// ---------------------------------------------------------------------------
extern "C" void kernel_launch(void* const* d_in, const int* in_sizes, int n_in,
                              void* d_out, int out_size, void* d_ws, size_t ws_size,
                              hipStream_t stream) {
    const float* x    = (const float*)d_in[0];
    const float* W_w  = (const float*)d_in[1];
    const float* W_b  = (const float*)d_in[2];
    const float* U_w  = (const float*)d_in[3];
    const float* U_b  = (const float*)d_in[4];
    const float* bias = (const float*)d_in[5];
    float* out = (float*)d_out;

    // ws: [0,64K) flags ; [64K, +256K) h0 ; then h1
    unsigned* bar = (unsigned*)d_ws;
    float* h0 = (float*)((char*)d_ws + 65536);
    float* h1 = h0 + (size_t)DIM * BATCH;

    hipMemsetAsync(d_ws, 0, 65536 + 2 * (size_t)DIM * BATCH * sizeof(float), stream);

    gemm_wx<<<dim3((32768 / 128) * (DIM / 128)), dim3(256), 0, stream>>>(x, W_w, W_b, out);

    static bool attr_done = false;
    if (!attr_done) {
        hipFuncSetAttribute((const void*)rnn_scan3,
                            hipFuncAttributeMaxDynamicSharedMemorySize, LDS_BYTES);
        attr_done = true;
    }

    void* args[] = {(void*)&U_w, (void*)&U_b, (void*)&bias,
                    (void*)&out, (void*)&h0, (void*)&h1, (void*)&bar};
    hipLaunchCooperativeKernel((void*)rnn_scan3, dim3(NBLK), dim3(NTHR), args,
                               LDS_BYTES, stream);
}